// Round 9
// baseline (610.880 us; speedup 1.0000x reference)
//
#include <hip/hip_runtime.h>
#include <math.h>

#define Tn 4096
#define Dm 1024
#define Hn 8
#define DH 128

typedef __bf16 bf16x8 __attribute__((ext_vector_type(8)));
typedef float f32x4 __attribute__((ext_vector_type(4)));

#define LOG2E 1.4426950408889634f
#define WEXP 0.025952563241307518f  // log2(10000)/512
#define WDECAY 0.31622776601683794f // 10000^(-128/1024): angle decay per 128-col KV tile
#define PIO2 1.5707963267948966f

#define MFMA(a, b, c) __builtin_amdgcn_mfma_f32_16x16x32_bf16((a), (b), (c), 0, 0, 0)

// async global->LDS 16B per lane; dest is wave-uniform base + lane*16
#define GLOAD_LDS(g, l) __builtin_amdgcn_global_load_lds( \
    (__attribute__((address_space(1))) void*)(void*)(g),  \
    (__attribute__((address_space(3))) void*)(l), 16, 0, 0)

// ---------------------------------------------------------------------------
// fp32 -> (hi, lo) bf16 split
__global__ __launch_bounds__(256)
void split_kernel(const float* __restrict__ in, __bf16* __restrict__ hi,
                  __bf16* __restrict__ lo, int n4) {
    int idx = blockIdx.x * 256 + threadIdx.x;
    if (idx >= n4) return;
    float4 v = ((const float4*)in)[idx];
    __attribute__((aligned(8))) __bf16 h[4], l[4];
    h[0] = (__bf16)v.x; h[1] = (__bf16)v.y; h[2] = (__bf16)v.z; h[3] = (__bf16)v.w;
    l[0] = (__bf16)(v.x - (float)h[0]);
    l[1] = (__bf16)(v.y - (float)h[1]);
    l[2] = (__bf16)(v.z - (float)h[2]);
    l[3] = (__bf16)(v.w - (float)h[3]);
    *(float2*)&hi[(size_t)idx * 4] = *(float2*)h;
    *(float2*)&lo[(size_t)idx * 4] = *(float2*)l;
}

// V[h][t][e] bf16 -> Vt[h][e][t] bf16
__global__ __launch_bounds__(256)
void vtrans_kernel(const __bf16* __restrict__ V, __bf16* __restrict__ Vt) {
    __shared__ __bf16 tile[64][80];
    int h = blockIdx.z, t0 = blockIdx.x * 64, e0 = blockIdx.y * 64;
    const __bf16* Vh = V + (size_t)h * Tn * DH;
    __bf16* Vth = Vt + (size_t)h * DH * Tn;
#pragma unroll
    for (int p = 0; p < 2; ++p) {
        int r = (threadIdx.x >> 3) + p * 32;
        int c = (threadIdx.x & 7) * 8;
        *(float4*)&tile[r][c] = *(const float4*)&Vh[(size_t)(t0 + r) * DH + e0 + c];
    }
    __syncthreads();
#pragma unroll
    for (int p = 0; p < 2; ++p) {
        int r = (threadIdx.x >> 3) + p * 32;
        int c = (threadIdx.x & 7) * 8;
        __attribute__((aligned(16))) __bf16 tmp[8];
#pragma unroll
        for (int j = 0; j < 8; ++j) tmp[j] = tile[c + j][r];
        *(float4*)&Vth[(size_t)(e0 + r) * Tn + t0 + c] = *(float4*)tmp;
    }
}

// ---------------------------------------------------------------------------
// Shared 128x128-tile NT GEMM body (BK=32, 4 waves 2x2, optional hi/lo 3-pass)
// global_load_lds width-16 staging into LINEAR [128][32] bf16 tiles.
// ---------------------------------------------------------------------------
__device__ __forceinline__
void gemm_body(__bf16 (*smem)[128 * 32],
               const __bf16* __restrict__ Ahi, const __bf16* __restrict__ Alo,
               const __bf16* __restrict__ Bhi, const __bf16* __restrict__ Blo,
               int ldA, int ldB, int K, int m0, int n0, f32x4 acc[4][4]) {
    int tid = threadIdx.x;
    int lane = tid & 63, wid = tid >> 6;
    int wm = (wid >> 1) * 64, wn = (wid & 1) * 64;
    int lm = lane & 15, q = lane >> 4;
    int lr = lane >> 2;          // row within 16-row chunk
    int lc = (lane & 3) * 8;     // col (bf16 units)
    const bool split = (Alo != nullptr);
    for (int k0 = 0; k0 < K; k0 += 32) {
        __syncthreads();
#pragma unroll
        for (int p = 0; p < 128; p += 64) {
            int rb = p + wid * 16;           // wave-uniform chunk base row
            int r = rb + lr;                 // per-lane global row
            GLOAD_LDS(&Ahi[(size_t)(m0 + r) * ldA + k0 + lc], &smem[0][rb * 32]);
            GLOAD_LDS(&Bhi[(size_t)(n0 + r) * ldB + k0 + lc], &smem[2][rb * 32]);
            if (split) {
                GLOAD_LDS(&Alo[(size_t)(m0 + r) * ldA + k0 + lc], &smem[1][rb * 32]);
                GLOAD_LDS(&Blo[(size_t)(n0 + r) * ldB + k0 + lc], &smem[3][rb * 32]);
            }
        }
        __syncthreads();
        bf16x8 ah[4], bh[4], al[4], bl[4];
#pragma unroll
        for (int mt = 0; mt < 4; ++mt) {
            ah[mt] = *(const bf16x8*)&smem[0][(wm + mt * 16 + lm) * 32 + q * 8];
            if (split)
                al[mt] = *(const bf16x8*)&smem[1][(wm + mt * 16 + lm) * 32 + q * 8];
        }
#pragma unroll
        for (int nt = 0; nt < 4; ++nt) {
            bh[nt] = *(const bf16x8*)&smem[2][(wn + nt * 16 + lm) * 32 + q * 8];
            if (split)
                bl[nt] = *(const bf16x8*)&smem[3][(wn + nt * 16 + lm) * 32 + q * 8];
        }
#pragma unroll
        for (int mt = 0; mt < 4; ++mt)
#pragma unroll
            for (int nt = 0; nt < 4; ++nt) {
                acc[mt][nt] = MFMA(ah[mt], bh[nt], acc[mt][nt]);
                if (split) {
                    acc[mt][nt] = MFMA(ah[mt], bl[nt], acc[mt][nt]);
                    acc[mt][nt] = MFMA(al[mt], bh[nt], acc[mt][nt]);
                }
            }
    }
}

// ---------------------------------------------------------------------------
// Fused QKV projection: blockIdx.z selects Q/K/V. Output in [h][t][e] layout,
// Q/K split hi/lo, V plain bf16. Epilogue v2: since n0 is 128-aligned, each
// block covers exactly one head (h0 = n0>>7) and contiguous [t][e] rows ->
// LDS-staged vectorized stores (float4 of 8 bf16, 256B/row) instead of the
// old 2B scattered stores.
// ---------------------------------------------------------------------------
__global__ __launch_bounds__(256)
void qkv_kernel(const __bf16* __restrict__ xhi, const __bf16* __restrict__ xlo,
                const __bf16* __restrict__ Wqh, const __bf16* __restrict__ Wql,
                const __bf16* __restrict__ Wkh, const __bf16* __restrict__ Wkl,
                const __bf16* __restrict__ Wvh, const __bf16* __restrict__ Wvl,
                __bf16* __restrict__ Qh, __bf16* __restrict__ Ql,
                __bf16* __restrict__ Kh, __bf16* __restrict__ Kl,
                __bf16* __restrict__ Vb) {
    __shared__ __align__(16) __bf16 smem[4][128 * 32];   // 32 KB
    int z = blockIdx.z;
    const __bf16* Bh = (z == 0) ? Wqh : (z == 1) ? Wkh : Wvh;
    const __bf16* Bl = (z == 0) ? Wql : (z == 1) ? Wkl : Wvl;
    __bf16* Oh = (z == 0) ? Qh : (z == 1) ? Kh : Vb;
    __bf16* Ol = (z == 0) ? Ql : (z == 1) ? Kl : nullptr;
    int m0 = blockIdx.y * 128, n0 = blockIdx.x * 128;
    int tid = threadIdx.x, lane = tid & 63, wid = tid >> 6;
    int wm = (wid >> 1) * 64, wn = (wid & 1) * 64;
    int lm = lane & 15, q = lane >> 4;
    f32x4 acc[4][4];
#pragma unroll
    for (int i = 0; i < 4; ++i)
#pragma unroll
        for (int j = 0; j < 4; ++j) acc[i][j] = (f32x4){0.f, 0.f, 0.f, 0.f};
    gemm_body(smem, xhi, xlo, Bh, Bl, Dm, Dm, Dm, m0, n0, acc);

    __bf16* St = (__bf16*)smem;           // [128][128] bf16 = 32 KB
    int h0 = n0 >> 7;
    int row = tid >> 1, half = (tid & 1) * 64;

    // ---- hi pass ----
    __syncthreads();
#pragma unroll
    for (int mt = 0; mt < 4; ++mt)
#pragma unroll
        for (int r = 0; r < 4; ++r)
#pragma unroll
            for (int nt = 0; nt < 4; ++nt)
                St[(wm + mt * 16 + q * 4 + r) * 128 + wn + nt * 16 + lm] =
                    (__bf16)acc[mt][nt][r];
    __syncthreads();
    {
        __bf16* dst = Oh + ((size_t)h0 * Tn + m0 + row) * DH + half;
        const __bf16* src = St + row * 128 + half;
#pragma unroll
        for (int j = 0; j < 8; ++j)
            *(float4*)&dst[j * 8] = *(const float4*)&src[j * 8];
    }
    // ---- lo pass ----
    if (Ol) {
        __syncthreads();
#pragma unroll
        for (int mt = 0; mt < 4; ++mt)
#pragma unroll
            for (int r = 0; r < 4; ++r)
#pragma unroll
                for (int nt = 0; nt < 4; ++nt) {
                    float v = acc[mt][nt][r];
                    __bf16 hv = (__bf16)v;
                    St[(wm + mt * 16 + q * 4 + r) * 128 + wn + nt * 16 + lm] =
                        (__bf16)(v - (float)hv);
                }
        __syncthreads();
        __bf16* dst = Ol + ((size_t)h0 * Tn + m0 + row) * DH + half;
        const __bf16* src = St + row * 128 + half;
#pragma unroll
        for (int j = 0; j < 8; ++j)
            *(float4*)&dst[j * 8] = *(const float4*)&src[j * 8];
    }
}

// ---------------------------------------------------------------------------
// Output projection: C = A B^T fp32 store
// ---------------------------------------------------------------------------
__global__ __launch_bounds__(256)
void gemm_out(const __bf16* __restrict__ Ahi, const __bf16* __restrict__ Alo,
              const __bf16* __restrict__ Bhi, const __bf16* __restrict__ Blo,
              float* __restrict__ C) {
    __shared__ __align__(16) __bf16 smem[4][128 * 32];   // 32 KB
    int m0 = blockIdx.y * 128, n0 = blockIdx.x * 128;
    int tid = threadIdx.x, lane = tid & 63, wid = tid >> 6;
    int wm = (wid >> 1) * 64, wn = (wid & 1) * 64;
    int lm = lane & 15, q = lane >> 4;
    f32x4 acc[4][4];
#pragma unroll
    for (int i = 0; i < 4; ++i)
#pragma unroll
        for (int j = 0; j < 4; ++j) acc[i][j] = (f32x4){0.f, 0.f, 0.f, 0.f};
    gemm_body(smem, Ahi, Alo, Bhi, Blo, Dm, Dm, Dm, m0, n0, acc);
#pragma unroll
    for (int mt = 0; mt < 4; ++mt)
#pragma unroll
        for (int r = 0; r < 4; ++r) {
            int grow = m0 + wm + mt * 16 + q * 4 + r;
#pragma unroll
            for (int nt = 0; nt < 4; ++nt)
                C[(size_t)grow * Dm + n0 + wn + nt * 16 + lm] = acc[mt][nt][r];
        }
}

// ---------------------------------------------------------------------------
// Flash attention v8 = v6 + depth-2 K register relay (ka/kb sets, statically
// unrolled). A K chunk is loaded at kc and committed to LDS at kc+2, so its
// L2 latency hides under TWO MFMA clusters (and, for the kc=2/3 loads, the
// whole softmax+PV phase into the next tile). +16 VGPRs — free at the
// 2-wave/SIMD occupancy (192-arch budget). Everything else frozen from v6
// (378 us, twice reproduced).
// ---------------------------------------------------------------------------
#define QK_STEP(SET, BUF, QIDX, NIT, NKC)                                     \
    {                                                                          \
        *(float4*)&Ks[BUF][0][sr][scc]      = SET##h0;                         \
        *(float4*)&Ks[BUF][1][sr][scc]      = SET##l0;                         \
        *(float4*)&Ks[BUF][0][sr + 64][scc] = SET##h1;                         \
        *(float4*)&Ks[BUF][1][sr + 64][scc] = SET##l1;                         \
        __syncthreads();                                                       \
        {                                                                      \
            size_t go0 = (size_t)((NIT) * 128 + sr) * DH + (NKC) * 32 + scc;   \
            size_t go1 = go0 + (size_t)64 * DH;                                \
            SET##h0 = *(const float4*)&Kh[go0];                                \
            SET##l0 = *(const float4*)&Kl[go0];                                \
            SET##h1 = *(const float4*)&Kh[go1];                                \
            SET##l1 = *(const float4*)&Kl[go1];                                \
        }                                                                      \
        __builtin_amdgcn_s_setprio(1);                                         \
        _Pragma("unroll")                                                      \
        for (int nt = 0; nt < 8; ++nt) {                                       \
            bf16x8 kbh = *(const bf16x8*)&Ks[BUF][0][nt * 16 + lm][q * 8];     \
            bf16x8 kbl = *(const bf16x8*)&Ks[BUF][1][nt * 16 + lm][q * 8];     \
            accS[nt] = MFMA(qfh[QIDX], kbh, accS[nt]);                         \
            accS[nt] = MFMA(qfh[QIDX], kbl, accS[nt]);                         \
            accS[nt] = MFMA(qfl[QIDX], kbh, accS[nt]);                         \
        }                                                                      \
        __builtin_amdgcn_s_setprio(0);                                         \
    }

__global__ __launch_bounds__(256, 2)
void flash_kernel(const __bf16* __restrict__ Qhi, const __bf16* __restrict__ Qlo,
                  const __bf16* __restrict__ Khi, const __bf16* __restrict__ Klo,
                  const __bf16* __restrict__ Vt, float* __restrict__ Opart,
                  float* __restrict__ mPart, float* __restrict__ lPart) {
    __shared__ __bf16 Ks[2][2][128][40];  // 40960 B  [buf][hi/lo][row][col]
    __shared__ __bf16 Ps[64][132];        // 16896 B
    int bid = blockIdx.x;
    int h = bid & 7;
    int g = (bid >> 3) & 1;
    int m0 = (bid >> 4) * 64;
    int it0 = g * 16;
    const size_t TD = (size_t)Tn * DH;
    const __bf16* Qh = Qhi + h * TD;
    const __bf16* Ql = Qlo + h * TD;
    const __bf16* Kh = Khi + h * TD;
    const __bf16* Kl = Klo + h * TD;
    const __bf16* Vh = Vt + h * TD;
    float* Og = Opart + (size_t)g * Tn * Dm;

    int tid = threadIdx.x;
    int lane = tid & 63, wid = tid >> 6;
    int lm = lane & 15, q = lane >> 4;
    int wr0 = wid * 16;

    // Q fragments in registers (hi + lo)
    bf16x8 qfh[4], qfl[4];
#pragma unroll
    for (int kc = 0; kc < 4; ++kc) {
        size_t o = (size_t)(m0 + wr0 + lm) * DH + kc * 32 + q * 8;
        qfh[kc] = *(const bf16x8*)&Qh[o];
        qfl[kc] = *(const bf16x8*)&Ql[o];
    }

    f32x4 accO[8];
#pragma unroll
    for (int nt = 0; nt < 8; ++nt) accO[nt] = (f32x4){0.f, 0.f, 0.f, 0.f};
    float mrow[4], lrow[4];
#pragma unroll
    for (int r = 0; r < 4; ++r) { mrow[r] = -3.0e38f; lrow[r] = 0.f; }

    int sr = tid >> 2;
    int scc = (tid & 3) * 8;
    bool iscos = (lm & 1);
    float wv[8];
#pragma unroll
    for (int nt = 0; nt < 8; ++nt)
        wv[nt] = exp2f(-(float)(((g << 11) + nt * 16 + lm) >> 1) * WEXP);
    float tf[4];
#pragma unroll
    for (int r = 0; r < 4; ++r) tf[r] = (float)(m0 + wr0 + q * 4 + r);

    // V fragment base offsets (per nt row; col advances with s0/kc)
    size_t voff[8];
#pragma unroll
    for (int nt = 0; nt < 8; ++nt)
        voff[nt] = (size_t)(nt * 16 + lm) * Tn + q * 8;

    // depth-2 K staging relay: set ka holds even-kc chunks, kb odd-kc chunks
    float4 kah0, kal0, kah1, kal1, kbh0, kbl0, kbh1, kbl1;
    {
        size_t g0 = (size_t)(it0 * 128 + sr) * DH + scc;     // (it0, kc=0)
        size_t g1 = g0 + (size_t)64 * DH;
        kah0 = *(const float4*)&Kh[g0]; kal0 = *(const float4*)&Kl[g0];
        kah1 = *(const float4*)&Kh[g1]; kal1 = *(const float4*)&Kl[g1];
        size_t h0_ = g0 + 32, h1_ = g1 + 32;                 // (it0, kc=1)
        kbh0 = *(const float4*)&Kh[h0_]; kbl0 = *(const float4*)&Kl[h0_];
        kbh1 = *(const float4*)&Kh[h1_]; kbl1 = *(const float4*)&Kl[h1_];
    }

    for (int it = it0; it < it0 + 16; ++it) {
        int s0 = it * 128;
        int itn = (it < it0 + 15) ? it + 1 : it;
        f32x4 accS[8];
#pragma unroll
        for (int nt = 0; nt < 8; ++nt) accS[nt] = (f32x4){0.f, 0.f, 0.f, 0.f};

        // ---- S = Q K^T: 4 kc steps, depth-2 relay ----
        QK_STEP(ka, 0, 0, it, 2)      // commit (it,0); load (it,2)
        QK_STEP(kb, 1, 1, it, 3)      // commit (it,1); load (it,3)
        QK_STEP(ka, 0, 2, itn, 0)     // commit (it,2); load (it+1,0)
        QK_STEP(kb, 1, 3, itn, 1)     // commit (it,3); load (it+1,1)

        // ---- prefetch V kc=0 frags; latency hides under the softmax ----
        bf16x8 vrel[8];
#pragma unroll
        for (int nt = 0; nt < 8; ++nt)
            vrel[nt] = *(const bf16x8*)&Vh[voff[nt] + s0];

        // ---- bias + online softmax (row state in 16-lane lm groups) ----
        float rmax[4];
#pragma unroll
        for (int r = 0; r < 4; ++r) {
            float mx = -3.0e38f;
#pragma unroll
            for (int nt = 0; nt < 8; ++nt) {
                float ang = tf[r] * wv[nt];
                float b = __sinf(iscos ? ang + PIO2 : ang);  // cos(x)=sin(x+pi/2)
                float v = accS[nt][r] + b;
                accS[nt][r] = v;
                mx = fmaxf(mx, v);
            }
            rmax[r] = mx;
        }
#pragma unroll
        for (int off = 1; off < 16; off <<= 1)
#pragma unroll
            for (int r = 0; r < 4; ++r)
                rmax[r] = fmaxf(rmax[r], __shfl_xor(rmax[r], off));
        float alpha[4], rsum[4];
#pragma unroll
        for (int r = 0; r < 4; ++r) {
            float mn = fmaxf(mrow[r], rmax[r]);
            alpha[r] = exp2f((mrow[r] - mn) * LOG2E);
            mrow[r] = mn;
            rsum[r] = 0.f;
        }
#pragma unroll
        for (int nt = 0; nt < 8; ++nt)
#pragma unroll
            for (int r = 0; r < 4; ++r) {
                float p = exp2f((accS[nt][r] - mrow[r]) * LOG2E);
                accS[nt][r] = p;
                rsum[r] += p;
            }
#pragma unroll
        for (int off = 1; off < 16; off <<= 1)
#pragma unroll
            for (int r = 0; r < 4; ++r)
                rsum[r] += __shfl_xor(rsum[r], off);
#pragma unroll
        for (int r = 0; r < 4; ++r)
            lrow[r] = lrow[r] * alpha[r] + rsum[r];
#pragma unroll
        for (int nt = 0; nt < 8; ++nt)
#pragma unroll
            for (int r = 0; r < 4; ++r)
                accO[nt][r] *= alpha[r];

        // ---- P relayout via LDS (intra-wave rows wr0..wr0+15; no barrier) ----
#pragma unroll
        for (int nt = 0; nt < 8; ++nt)
#pragma unroll
            for (int r = 0; r < 4; ++r)
                Ps[wr0 + q * 4 + r][nt * 16 + lm] = (__bf16)accS[nt][r];

        // ---- O += P @ V (V frags via register relay: use kc, fetch kc+1) ----
#pragma unroll
        for (int kc = 0; kc < 4; ++kc) {
            bf16x8 pa = *(const bf16x8*)&Ps[wr0 + lm][kc * 32 + q * 8];
            bf16x8 vcur[8];
#pragma unroll
            for (int nt = 0; nt < 8; ++nt) vcur[nt] = vrel[nt];
            if (kc < 3) {
#pragma unroll
                for (int nt = 0; nt < 8; ++nt)
                    vrel[nt] = *(const bf16x8*)&Vh[voff[nt] + s0 + (kc + 1) * 32];
            }
            __builtin_amdgcn_s_setprio(1);
#pragma unroll
            for (int nt = 0; nt < 8; ++nt)
                accO[nt] = MFMA(pa, vcur[nt], accO[nt]);
            __builtin_amdgcn_s_setprio(0);
        }

        // advance bias frequencies to next 128-col tile
#pragma unroll
        for (int nt = 0; nt < 8; ++nt) wv[nt] *= WDECAY;
    }

    // ---- epilogue: unnormalized O partial + per-row m,l ----
#pragma unroll
    for (int r = 0; r < 4; ++r) {
        int t = m0 + wr0 + q * 4 + r;
#pragma unroll
        for (int nt = 0; nt < 8; ++nt)
            Og[(size_t)t * Dm + h * DH + nt * 16 + lm] = accO[nt][r];
        if (lm == 0) {
            mPart[(size_t)(g * Hn + h) * Tn + t] = mrow[r];
            lPart[(size_t)(g * Hn + h) * Tn + t] = lrow[r];
        }
    }
}

// ---------------------------------------------------------------------------
// Combine the two KV-half partials: y = (w0*O0 + w1*O1) / (w0*l0 + w1*l1),
// w_g = e^(m_g - m). Writes y directly as bf16 hi/lo (feeds gemm_out) and
// exports head-7 combined m,l for att_kernel.
// ---------------------------------------------------------------------------
__global__ __launch_bounds__(256)
void combine_kernel(const float* __restrict__ Opart,
                    const float* __restrict__ mPart, const float* __restrict__ lPart,
                    __bf16* __restrict__ yhi, __bf16* __restrict__ ylo,
                    float* __restrict__ mM, float* __restrict__ lL) {
    int idx = blockIdx.x * 256 + threadIdx.x;   // one float4 of y per thread
    int t = idx >> 8;
    int c4 = idx & 255;
    int c = c4 * 4;
    int h = c >> 7;
    float m0 = mPart[(size_t)h * Tn + t];
    float m1 = mPart[(size_t)(Hn + h) * Tn + t];
    float l0 = lPart[(size_t)h * Tn + t];
    float l1 = lPart[(size_t)(Hn + h) * Tn + t];
    float m = fmaxf(m0, m1);
    float w0 = exp2f((m0 - m) * LOG2E);
    float w1 = exp2f((m1 - m) * LOG2E);
    float l = l0 * w0 + l1 * w1;
    float inv = 1.0f / l;
    w0 *= inv; w1 *= inv;
    float4 a = ((const float4*)Opart)[idx];
    float4 b = ((const float4*)(Opart + (size_t)Tn * Dm))[idx];
    float y[4] = {a.x * w0 + b.x * w1, a.y * w0 + b.y * w1,
                  a.z * w0 + b.z * w1, a.w * w0 + b.w * w1};
    __attribute__((aligned(8))) __bf16 hh[4], ll[4];
#pragma unroll
    for (int j = 0; j < 4; ++j) {
        hh[j] = (__bf16)y[j];
        ll[j] = (__bf16)(y[j] - (float)hh[j]);
    }
    *(float2*)&yhi[(size_t)idx * 4] = *(float2*)hh;
    *(float2*)&ylo[(size_t)idx * 4] = *(float2*)ll;
    if (h == 7 && (c & 127) == 0) { mM[t] = m; lL[t] = l; }
}

// ---------------------------------------------------------------------------
// att[-1] regeneration: S7 = Q7 K7^T (3-pass) + bias, att = exp2((S-m)lg2e)/l,
// stored via LDS-staged coalesced epilogue (two 64-col phases).
// ---------------------------------------------------------------------------
__global__ __launch_bounds__(256)
void att_kernel(const __bf16* __restrict__ Ahi, const __bf16* __restrict__ Alo,
                const __bf16* __restrict__ Bhi, const __bf16* __restrict__ Blo,
                const float* __restrict__ mM, const float* __restrict__ lL,
                float* __restrict__ att) {
    __shared__ __align__(16) char shraw[34816];  // max(32768 gemm, 34816 Ls)
    __bf16 (*smem)[128 * 32] = reinterpret_cast<__bf16(*)[128 * 32]>(shraw);
    float (*Ls)[68] = reinterpret_cast<float(*)[68]>(shraw);

    int m0 = blockIdx.y * 128, n0 = blockIdx.x * 128;
    int tid = threadIdx.x, lane = tid & 63, wid = tid >> 6;
    int wm = (wid >> 1) * 64, wn = (wid & 1) * 64;
    int lm = lane & 15, q = lane >> 4;
    f32x4 acc[4][4];
#pragma unroll
    for (int i = 0; i < 4; ++i)
#pragma unroll
        for (int j = 0; j < 4; ++j) acc[i][j] = (f32x4){0.f, 0.f, 0.f, 0.f};
    gemm_body(smem, Ahi, Alo, Bhi, Blo, DH, DH, DH, m0, n0, acc);

    // normalize in-register
    float wv[4];
#pragma unroll
    for (int nt = 0; nt < 4; ++nt) {
        int s = n0 + wn + nt * 16 + lm;
        wv[nt] = exp2f(-(float)(s >> 1) * WEXP);
    }
    int par = lm & 1;
#pragma unroll
    for (int mt = 0; mt < 4; ++mt)
#pragma unroll
        for (int r = 0; r < 4; ++r) {
            int t = m0 + wm + mt * 16 + q * 4 + r;
            float tf = (float)t;
            float mr = mM[t];
            float linv = 1.0f / lL[t];
#pragma unroll
            for (int nt = 0; nt < 4; ++nt) {
                float ang = tf * wv[nt];
                float bias = __sinf(par ? ang + PIO2 : ang);  // cos = sin(+pi/2)
                acc[mt][nt][r] = exp2f((acc[mt][nt][r] + bias - mr) * LOG2E) * linv;
            }
        }

    // two-phase LDS-staged coalesced store (cols wn = p*64)
#pragma unroll
    for (int p = 0; p < 2; ++p) {
        __syncthreads();
        if ((wid & 1) == p) {
#pragma unroll
            for (int mt = 0; mt < 4; ++mt)
#pragma unroll
                for (int r = 0; r < 4; ++r)
#pragma unroll
                    for (int nt = 0; nt < 4; ++nt)
                        Ls[wm + mt * 16 + q * 4 + r][nt * 16 + lm] = acc[mt][nt][r];
        }
        __syncthreads();
#pragma unroll
        for (int j = 0; j < 8; ++j) {
            int row = j * 16 + (tid >> 4);
            int col = (tid & 15) * 4;
            float4 v = *(float4*)&Ls[row][col];
            *(float4*)&att[(size_t)(m0 + row) * Tn + n0 + p * 64 + col] = v;
        }
    }
}

// ---------------------------------------------------------------------------
extern "C" void kernel_launch(void* const* d_in, const int* in_sizes, int n_in,
                              void* d_out, int out_size, void* d_ws, size_t ws_size,
                              hipStream_t stream) {
    (void)in_sizes; (void)n_in; (void)out_size; (void)ws_size;
    const float* x    = (const float*)d_in[0];
    const float* Wq   = (const float*)d_in[1];
    const float* Wk   = (const float*)d_in[2];
    const float* Wv   = (const float*)d_in[3];
    const float* Wout = (const float*)d_in[4];

    float* out_y   = (float*)d_out;              // [4096][1024]
    float* out_att = out_y + (size_t)Tn * Dm;    // [4096][4096]

    const size_t MB = 1ull << 20;
    char* W = (char*)d_ws;
    __bf16* xhi  = (__bf16*)(W + 0 * MB);
    __bf16* xlo  = (__bf16*)(W + 8 * MB);
    __bf16* Wqhi = (__bf16*)(W + 16 * MB);
    __bf16* Wqlo = (__bf16*)(W + 18 * MB);
    __bf16* Wkhi = (__bf16*)(W + 20 * MB);
    __bf16* Wklo = (__bf16*)(W + 22 * MB);
    __bf16* Wvhi = (__bf16*)(W + 24 * MB);
    __bf16* Wvlo = (__bf16*)(W + 26 * MB);
    __bf16* Wohi = (__bf16*)(W + 28 * MB);
    __bf16* Wolo = (__bf16*)(W + 30 * MB);
    __bf16* Qhi  = (__bf16*)(W + 32 * MB);   // [H][T][DH]
    __bf16* Qlo  = (__bf16*)(W + 40 * MB);
    __bf16* Khi  = (__bf16*)(W + 48 * MB);
    __bf16* Klo  = (__bf16*)(W + 56 * MB);
    __bf16* Vb   = (__bf16*)(W + 64 * MB);   // [H][T][DH]
    __bf16* Vt   = (__bf16*)(W + 72 * MB);   // [H][DH][T]
    float*  mM    = (float*)(W + 80 * MB);   // [T]
    float*  lL    = (float*)(W + 81 * MB);   // [T]
    float*  mPart = (float*)(W + 82 * MB);   // [2][H][T]
    float*  lPart = (float*)(W + 83 * MB);   // [2][H][T]
    float*  Opart = (float*)(W + 84 * MB);   // [2][T][1024] fp32 (32 MB)
    __bf16* yhhi  = (__bf16*)(W + 116 * MB); // [T][1024] bf16
    __bf16* yhlo  = (__bf16*)(W + 124 * MB);

    dim3 blk(256);

    split_kernel<<<dim3(Tn * Dm / 4 / 256), blk, 0, stream>>>(x, xhi, xlo, Tn * Dm / 4);
    split_kernel<<<dim3(Dm * Dm / 4 / 256), blk, 0, stream>>>(Wq, Wqhi, Wqlo, Dm * Dm / 4);
    split_kernel<<<dim3(Dm * Dm / 4 / 256), blk, 0, stream>>>(Wk, Wkhi, Wklo, Dm * Dm / 4);
    split_kernel<<<dim3(Dm * Dm / 4 / 256), blk, 0, stream>>>(Wv, Wvhi, Wvlo, Dm * Dm / 4);
    split_kernel<<<dim3(Dm * Dm / 4 / 256), blk, 0, stream>>>(Wout, Wohi, Wolo, Dm * Dm / 4);

    // fused QKV projection (z: 0=Q split, 1=K split, 2=V plain)
    qkv_kernel<<<dim3(Dm / 128, Tn / 128, 3), blk, 0, stream>>>(
        xhi, xlo, Wqhi, Wqlo, Wkhi, Wklo, Wvhi, Wvlo,
        Qhi, Qlo, Khi, Klo, Vb);
    vtrans_kernel<<<dim3(Tn / 64, DH / 64, Hn), blk, 0, stream>>>(Vb, Vt);

    // flash attention v8: v6 + depth-2 K relay
    flash_kernel<<<dim3(1024), blk, 0, stream>>>(Qhi, Qlo, Khi, Klo, Vt,
                                                 Opart, mPart, lPart);

    // merge KV halves -> y (bf16 hi/lo) + head-7 m,l
    combine_kernel<<<dim3(Tn * Dm / 4 / 256), blk, 0, stream>>>(
        Opart, mPart, lPart, yhhi, yhlo, mM, lL);

    // att[-1] regeneration from head-7 m,l
    const size_t TD = (size_t)Tn * DH;
    att_kernel<<<dim3(Tn / 128, Tn / 128), blk, 0, stream>>>(
        Qhi + 7 * TD, Qlo + 7 * TD, Khi + 7 * TD, Klo + 7 * TD, mM, lL, out_att);

    // output projection
    gemm_out<<<dim3(Dm / 128, Tn / 128), blk, 0, stream>>>(yhhi, yhlo, Wohi, Wolo, out_y);
}

// Round 10
// 578.223 us; speedup vs baseline: 1.0565x; 1.0565x over previous
//
#include <hip/hip_runtime.h>
#include <math.h>

#define Tn 4096
#define Dm 1024
#define Hn 8
#define DH 128

typedef __bf16 bf16x8 __attribute__((ext_vector_type(8)));
typedef float f32x4 __attribute__((ext_vector_type(4)));

#define LOG2E 1.4426950408889634f
#define WEXP 0.025952563241307518f  // log2(10000)/512
#define WDECAY 0.31622776601683794f // 10000^(-128/1024): angle decay per 128-col KV tile
#define PIO2 1.5707963267948966f

#define MFMA(a, b, c) __builtin_amdgcn_mfma_f32_16x16x32_bf16((a), (b), (c), 0, 0, 0)

// async global->LDS 16B per lane; dest is wave-uniform base + lane*16
#define GLOAD_LDS(g, l) __builtin_amdgcn_global_load_lds( \
    (__attribute__((address_space(1))) void*)(void*)(g),  \
    (__attribute__((address_space(3))) void*)(l), 16, 0, 0)

// ---------------------------------------------------------------------------
// fp32 -> (hi, lo) bf16 split
__global__ __launch_bounds__(256)
void split_kernel(const float* __restrict__ in, __bf16* __restrict__ hi,
                  __bf16* __restrict__ lo, int n4) {
    int idx = blockIdx.x * 256 + threadIdx.x;
    if (idx >= n4) return;
    float4 v = ((const float4*)in)[idx];
    __attribute__((aligned(8))) __bf16 h[4], l[4];
    h[0] = (__bf16)v.x; h[1] = (__bf16)v.y; h[2] = (__bf16)v.z; h[3] = (__bf16)v.w;
    l[0] = (__bf16)(v.x - (float)h[0]);
    l[1] = (__bf16)(v.y - (float)h[1]);
    l[2] = (__bf16)(v.z - (float)h[2]);
    l[3] = (__bf16)(v.w - (float)h[3]);
    *(float2*)&hi[(size_t)idx * 4] = *(float2*)h;
    *(float2*)&lo[(size_t)idx * 4] = *(float2*)l;
}

// V[h][t][e] bf16 -> Vt[h][e][t] bf16
__global__ __launch_bounds__(256)
void vtrans_kernel(const __bf16* __restrict__ V, __bf16* __restrict__ Vt) {
    __shared__ __bf16 tile[64][80];
    int h = blockIdx.z, t0 = blockIdx.x * 64, e0 = blockIdx.y * 64;
    const __bf16* Vh = V + (size_t)h * Tn * DH;
    __bf16* Vth = Vt + (size_t)h * DH * Tn;
#pragma unroll
    for (int p = 0; p < 2; ++p) {
        int r = (threadIdx.x >> 3) + p * 32;
        int c = (threadIdx.x & 7) * 8;
        *(float4*)&tile[r][c] = *(const float4*)&Vh[(size_t)(t0 + r) * DH + e0 + c];
    }
    __syncthreads();
#pragma unroll
    for (int p = 0; p < 2; ++p) {
        int r = (threadIdx.x >> 3) + p * 32;
        int c = (threadIdx.x & 7) * 8;
        __attribute__((aligned(16))) __bf16 tmp[8];
#pragma unroll
        for (int j = 0; j < 8; ++j) tmp[j] = tile[c + j][r];
        *(float4*)&Vth[(size_t)(e0 + r) * Tn + t0 + c] = *(float4*)tmp;
    }
}

// ---------------------------------------------------------------------------
// Shared 128x128-tile NT GEMM body (BK=32, 4 waves 2x2, optional hi/lo 3-pass)
// global_load_lds width-16 staging into LINEAR [128][32] bf16 tiles.
// ---------------------------------------------------------------------------
__device__ __forceinline__
void gemm_body(__bf16 (*smem)[128 * 32],
               const __bf16* __restrict__ Ahi, const __bf16* __restrict__ Alo,
               const __bf16* __restrict__ Bhi, const __bf16* __restrict__ Blo,
               int ldA, int ldB, int K, int m0, int n0, f32x4 acc[4][4]) {
    int tid = threadIdx.x;
    int lane = tid & 63, wid = tid >> 6;
    int wm = (wid >> 1) * 64, wn = (wid & 1) * 64;
    int lm = lane & 15, q = lane >> 4;
    int lr = lane >> 2;          // row within 16-row chunk
    int lc = (lane & 3) * 8;     // col (bf16 units)
    const bool split = (Alo != nullptr);
    for (int k0 = 0; k0 < K; k0 += 32) {
        __syncthreads();
#pragma unroll
        for (int p = 0; p < 128; p += 64) {
            int rb = p + wid * 16;           // wave-uniform chunk base row
            int r = rb + lr;                 // per-lane global row
            GLOAD_LDS(&Ahi[(size_t)(m0 + r) * ldA + k0 + lc], &smem[0][rb * 32]);
            GLOAD_LDS(&Bhi[(size_t)(n0 + r) * ldB + k0 + lc], &smem[2][rb * 32]);
            if (split) {
                GLOAD_LDS(&Alo[(size_t)(m0 + r) * ldA + k0 + lc], &smem[1][rb * 32]);
                GLOAD_LDS(&Blo[(size_t)(n0 + r) * ldB + k0 + lc], &smem[3][rb * 32]);
            }
        }
        __syncthreads();
        bf16x8 ah[4], bh[4], al[4], bl[4];
#pragma unroll
        for (int mt = 0; mt < 4; ++mt) {
            ah[mt] = *(const bf16x8*)&smem[0][(wm + mt * 16 + lm) * 32 + q * 8];
            if (split)
                al[mt] = *(const bf16x8*)&smem[1][(wm + mt * 16 + lm) * 32 + q * 8];
        }
#pragma unroll
        for (int nt = 0; nt < 4; ++nt) {
            bh[nt] = *(const bf16x8*)&smem[2][(wn + nt * 16 + lm) * 32 + q * 8];
            if (split)
                bl[nt] = *(const bf16x8*)&smem[3][(wn + nt * 16 + lm) * 32 + q * 8];
        }
#pragma unroll
        for (int mt = 0; mt < 4; ++mt)
#pragma unroll
            for (int nt = 0; nt < 4; ++nt) {
                acc[mt][nt] = MFMA(ah[mt], bh[nt], acc[mt][nt]);
                if (split) {
                    acc[mt][nt] = MFMA(ah[mt], bl[nt], acc[mt][nt]);
                    acc[mt][nt] = MFMA(al[mt], bh[nt], acc[mt][nt]);
                }
            }
    }
}

// ---------------------------------------------------------------------------
// Fused QKV projection: blockIdx.z selects Q/K/V. Output in [h][t][e] layout,
// Q/K split hi/lo, V plain bf16. Epilogue: r8 direct-store version (the r9
// LDS-staged variant regressed ~28 us: scalar ds_write_b16 relayout hits only
// 8 banks with 2 lanes/dword + 3 extra barriers — reverted).
// ---------------------------------------------------------------------------
__global__ __launch_bounds__(256)
void qkv_kernel(const __bf16* __restrict__ xhi, const __bf16* __restrict__ xlo,
                const __bf16* __restrict__ Wqh, const __bf16* __restrict__ Wql,
                const __bf16* __restrict__ Wkh, const __bf16* __restrict__ Wkl,
                const __bf16* __restrict__ Wvh, const __bf16* __restrict__ Wvl,
                __bf16* __restrict__ Qh, __bf16* __restrict__ Ql,
                __bf16* __restrict__ Kh, __bf16* __restrict__ Kl,
                __bf16* __restrict__ Vb) {
    __shared__ __align__(16) __bf16 smem[4][128 * 32];   // 32 KB
    int z = blockIdx.z;
    const __bf16* Bh = (z == 0) ? Wqh : (z == 1) ? Wkh : Wvh;
    const __bf16* Bl = (z == 0) ? Wql : (z == 1) ? Wkl : Wvl;
    __bf16* Oh = (z == 0) ? Qh : (z == 1) ? Kh : Vb;
    __bf16* Ol = (z == 0) ? Ql : (z == 1) ? Kl : nullptr;
    int m0 = blockIdx.y * 128, n0 = blockIdx.x * 128;
    int tid = threadIdx.x, lane = tid & 63, wid = tid >> 6;
    int wm = (wid >> 1) * 64, wn = (wid & 1) * 64;
    int lm = lane & 15, q = lane >> 4;
    f32x4 acc[4][4];
#pragma unroll
    for (int i = 0; i < 4; ++i)
#pragma unroll
        for (int j = 0; j < 4; ++j) acc[i][j] = (f32x4){0.f, 0.f, 0.f, 0.f};
    gemm_body(smem, xhi, xlo, Bh, Bl, Dm, Dm, Dm, m0, n0, acc);
#pragma unroll
    for (int mt = 0; mt < 4; ++mt)
#pragma unroll
        for (int r = 0; r < 4; ++r) {
            int grow = m0 + wm + mt * 16 + q * 4 + r;
#pragma unroll
            for (int nt = 0; nt < 4; ++nt) {
                int gc = n0 + wn + nt * 16 + lm;
                int h = gc >> 7, e = gc & 127;
                size_t o = ((size_t)h * Tn + grow) * DH + e;
                float v = acc[mt][nt][r];
                __bf16 hv = (__bf16)v;
                Oh[o] = hv;
                if (Ol) Ol[o] = (__bf16)(v - (float)hv);
            }
        }
}

// ---------------------------------------------------------------------------
// Output projection: C = A B^T fp32 store
// ---------------------------------------------------------------------------
__global__ __launch_bounds__(256)
void gemm_out(const __bf16* __restrict__ Ahi, const __bf16* __restrict__ Alo,
              const __bf16* __restrict__ Bhi, const __bf16* __restrict__ Blo,
              float* __restrict__ C) {
    __shared__ __align__(16) __bf16 smem[4][128 * 32];   // 32 KB
    int m0 = blockIdx.y * 128, n0 = blockIdx.x * 128;
    int tid = threadIdx.x, lane = tid & 63, wid = tid >> 6;
    int wm = (wid >> 1) * 64, wn = (wid & 1) * 64;
    int lm = lane & 15, q = lane >> 4;
    f32x4 acc[4][4];
#pragma unroll
    for (int i = 0; i < 4; ++i)
#pragma unroll
        for (int j = 0; j < 4; ++j) acc[i][j] = (f32x4){0.f, 0.f, 0.f, 0.f};
    gemm_body(smem, Ahi, Alo, Bhi, Blo, Dm, Dm, Dm, m0, n0, acc);
#pragma unroll
    for (int mt = 0; mt < 4; ++mt)
#pragma unroll
        for (int r = 0; r < 4; ++r) {
            int grow = m0 + wm + mt * 16 + q * 4 + r;
#pragma unroll
            for (int nt = 0; nt < 4; ++nt)
                C[(size_t)grow * Dm + n0 + wn + nt * 16 + lm] = acc[mt][nt][r];
        }
}

// ---------------------------------------------------------------------------
// Flash attention v8 (FROZEN — 351 us measured r9) = v6 + depth-2 K register
// relay (ka/kb sets, statically unrolled). A K chunk is loaded at kc and
// committed to LDS at kc+2, so its L2 latency hides under TWO MFMA clusters
// (and, for kc=2/3, the whole softmax+PV phase into the next tile).
// ---------------------------------------------------------------------------
#define QK_STEP(SET, BUF, QIDX, NIT, NKC)                                     \
    {                                                                          \
        *(float4*)&Ks[BUF][0][sr][scc]      = SET##h0;                         \
        *(float4*)&Ks[BUF][1][sr][scc]      = SET##l0;                         \
        *(float4*)&Ks[BUF][0][sr + 64][scc] = SET##h1;                         \
        *(float4*)&Ks[BUF][1][sr + 64][scc] = SET##l1;                         \
        __syncthreads();                                                       \
        {                                                                      \
            size_t go0 = (size_t)((NIT) * 128 + sr) * DH + (NKC) * 32 + scc;   \
            size_t go1 = go0 + (size_t)64 * DH;                                \
            SET##h0 = *(const float4*)&Kh[go0];                                \
            SET##l0 = *(const float4*)&Kl[go0];                                \
            SET##h1 = *(const float4*)&Kh[go1];                                \
            SET##l1 = *(const float4*)&Kl[go1];                                \
        }                                                                      \
        __builtin_amdgcn_s_setprio(1);                                         \
        _Pragma("unroll")                                                      \
        for (int nt = 0; nt < 8; ++nt) {                                       \
            bf16x8 kbh = *(const bf16x8*)&Ks[BUF][0][nt * 16 + lm][q * 8];     \
            bf16x8 kbl = *(const bf16x8*)&Ks[BUF][1][nt * 16 + lm][q * 8];     \
            accS[nt] = MFMA(qfh[QIDX], kbh, accS[nt]);                         \
            accS[nt] = MFMA(qfh[QIDX], kbl, accS[nt]);                         \
            accS[nt] = MFMA(qfl[QIDX], kbh, accS[nt]);                         \
        }                                                                      \
        __builtin_amdgcn_s_setprio(0);                                         \
    }

__global__ __launch_bounds__(256, 2)
void flash_kernel(const __bf16* __restrict__ Qhi, const __bf16* __restrict__ Qlo,
                  const __bf16* __restrict__ Khi, const __bf16* __restrict__ Klo,
                  const __bf16* __restrict__ Vt, float* __restrict__ Opart,
                  float* __restrict__ mPart, float* __restrict__ lPart) {
    __shared__ __bf16 Ks[2][2][128][40];  // 40960 B  [buf][hi/lo][row][col]
    __shared__ __bf16 Ps[64][132];        // 16896 B
    int bid = blockIdx.x;
    int h = bid & 7;
    int g = (bid >> 3) & 1;
    int m0 = (bid >> 4) * 64;
    int it0 = g * 16;
    const size_t TD = (size_t)Tn * DH;
    const __bf16* Qh = Qhi + h * TD;
    const __bf16* Ql = Qlo + h * TD;
    const __bf16* Kh = Khi + h * TD;
    const __bf16* Kl = Klo + h * TD;
    const __bf16* Vh = Vt + h * TD;
    float* Og = Opart + (size_t)g * Tn * Dm;

    int tid = threadIdx.x;
    int lane = tid & 63, wid = tid >> 6;
    int lm = lane & 15, q = lane >> 4;
    int wr0 = wid * 16;

    // Q fragments in registers (hi + lo)
    bf16x8 qfh[4], qfl[4];
#pragma unroll
    for (int kc = 0; kc < 4; ++kc) {
        size_t o = (size_t)(m0 + wr0 + lm) * DH + kc * 32 + q * 8;
        qfh[kc] = *(const bf16x8*)&Qh[o];
        qfl[kc] = *(const bf16x8*)&Ql[o];
    }

    f32x4 accO[8];
#pragma unroll
    for (int nt = 0; nt < 8; ++nt) accO[nt] = (f32x4){0.f, 0.f, 0.f, 0.f};
    float mrow[4], lrow[4];
#pragma unroll
    for (int r = 0; r < 4; ++r) { mrow[r] = -3.0e38f; lrow[r] = 0.f; }

    int sr = tid >> 2;
    int scc = (tid & 3) * 8;
    bool iscos = (lm & 1);
    float wv[8];
#pragma unroll
    for (int nt = 0; nt < 8; ++nt)
        wv[nt] = exp2f(-(float)(((g << 11) + nt * 16 + lm) >> 1) * WEXP);
    float tf[4];
#pragma unroll
    for (int r = 0; r < 4; ++r) tf[r] = (float)(m0 + wr0 + q * 4 + r);

    // V fragment base offsets (per nt row; col advances with s0/kc)
    size_t voff[8];
#pragma unroll
    for (int nt = 0; nt < 8; ++nt)
        voff[nt] = (size_t)(nt * 16 + lm) * Tn + q * 8;

    // depth-2 K staging relay: set ka holds even-kc chunks, kb odd-kc chunks
    float4 kah0, kal0, kah1, kal1, kbh0, kbl0, kbh1, kbl1;
    {
        size_t g0 = (size_t)(it0 * 128 + sr) * DH + scc;     // (it0, kc=0)
        size_t g1 = g0 + (size_t)64 * DH;
        kah0 = *(const float4*)&Kh[g0]; kal0 = *(const float4*)&Kl[g0];
        kah1 = *(const float4*)&Kh[g1]; kal1 = *(const float4*)&Kl[g1];
        size_t h0_ = g0 + 32, h1_ = g1 + 32;                 // (it0, kc=1)
        kbh0 = *(const float4*)&Kh[h0_]; kbl0 = *(const float4*)&Kl[h0_];
        kbh1 = *(const float4*)&Kh[h1_]; kbl1 = *(const float4*)&Kl[h1_];
    }

    for (int it = it0; it < it0 + 16; ++it) {
        int s0 = it * 128;
        int itn = (it < it0 + 15) ? it + 1 : it;
        f32x4 accS[8];
#pragma unroll
        for (int nt = 0; nt < 8; ++nt) accS[nt] = (f32x4){0.f, 0.f, 0.f, 0.f};

        // ---- S = Q K^T: 4 kc steps, depth-2 relay ----
        QK_STEP(ka, 0, 0, it, 2)      // commit (it,0); load (it,2)
        QK_STEP(kb, 1, 1, it, 3)      // commit (it,1); load (it,3)
        QK_STEP(ka, 0, 2, itn, 0)     // commit (it,2); load (it+1,0)
        QK_STEP(kb, 1, 3, itn, 1)     // commit (it,3); load (it+1,1)

        // ---- prefetch V kc=0 frags; latency hides under the softmax ----
        bf16x8 vrel[8];
#pragma unroll
        for (int nt = 0; nt < 8; ++nt)
            vrel[nt] = *(const bf16x8*)&Vh[voff[nt] + s0];

        // ---- bias + online softmax (row state in 16-lane lm groups) ----
        float rmax[4];
#pragma unroll
        for (int r = 0; r < 4; ++r) {
            float mx = -3.0e38f;
#pragma unroll
            for (int nt = 0; nt < 8; ++nt) {
                float ang = tf[r] * wv[nt];
                float b = __sinf(iscos ? ang + PIO2 : ang);  // cos(x)=sin(x+pi/2)
                float v = accS[nt][r] + b;
                accS[nt][r] = v;
                mx = fmaxf(mx, v);
            }
            rmax[r] = mx;
        }
#pragma unroll
        for (int off = 1; off < 16; off <<= 1)
#pragma unroll
            for (int r = 0; r < 4; ++r)
                rmax[r] = fmaxf(rmax[r], __shfl_xor(rmax[r], off));
        float alpha[4], rsum[4];
#pragma unroll
        for (int r = 0; r < 4; ++r) {
            float mn = fmaxf(mrow[r], rmax[r]);
            alpha[r] = exp2f((mrow[r] - mn) * LOG2E);
            mrow[r] = mn;
            rsum[r] = 0.f;
        }
#pragma unroll
        for (int nt = 0; nt < 8; ++nt)
#pragma unroll
            for (int r = 0; r < 4; ++r) {
                float p = exp2f((accS[nt][r] - mrow[r]) * LOG2E);
                accS[nt][r] = p;
                rsum[r] += p;
            }
#pragma unroll
        for (int off = 1; off < 16; off <<= 1)
#pragma unroll
            for (int r = 0; r < 4; ++r)
                rsum[r] += __shfl_xor(rsum[r], off);
#pragma unroll
        for (int r = 0; r < 4; ++r)
            lrow[r] = lrow[r] * alpha[r] + rsum[r];
#pragma unroll
        for (int nt = 0; nt < 8; ++nt)
#pragma unroll
            for (int r = 0; r < 4; ++r)
                accO[nt][r] *= alpha[r];

        // ---- P relayout via LDS (intra-wave rows wr0..wr0+15; no barrier) ----
#pragma unroll
        for (int nt = 0; nt < 8; ++nt)
#pragma unroll
            for (int r = 0; r < 4; ++r)
                Ps[wr0 + q * 4 + r][nt * 16 + lm] = (__bf16)accS[nt][r];

        // ---- O += P @ V (V frags via register relay: use kc, fetch kc+1) ----
#pragma unroll
        for (int kc = 0; kc < 4; ++kc) {
            bf16x8 pa = *(const bf16x8*)&Ps[wr0 + lm][kc * 32 + q * 8];
            bf16x8 vcur[8];
#pragma unroll
            for (int nt = 0; nt < 8; ++nt) vcur[nt] = vrel[nt];
            if (kc < 3) {
#pragma unroll
                for (int nt = 0; nt < 8; ++nt)
                    vrel[nt] = *(const bf16x8*)&Vh[voff[nt] + s0 + (kc + 1) * 32];
            }
            __builtin_amdgcn_s_setprio(1);
#pragma unroll
            for (int nt = 0; nt < 8; ++nt)
                accO[nt] = MFMA(pa, vcur[nt], accO[nt]);
            __builtin_amdgcn_s_setprio(0);
        }

        // advance bias frequencies to next 128-col tile
#pragma unroll
        for (int nt = 0; nt < 8; ++nt) wv[nt] *= WDECAY;
    }

    // ---- epilogue: unnormalized O partial + per-row m,l ----
#pragma unroll
    for (int r = 0; r < 4; ++r) {
        int t = m0 + wr0 + q * 4 + r;
#pragma unroll
        for (int nt = 0; nt < 8; ++nt)
            Og[(size_t)t * Dm + h * DH + nt * 16 + lm] = accO[nt][r];
        if (lm == 0) {
            mPart[(size_t)(g * Hn + h) * Tn + t] = mrow[r];
            lPart[(size_t)(g * Hn + h) * Tn + t] = lrow[r];
        }
    }
}

// ---------------------------------------------------------------------------
// Combine the two KV-half partials: y = (w0*O0 + w1*O1) / (w0*l0 + w1*l1),
// w_g = e^(m_g - m). Writes y directly as bf16 hi/lo (feeds gemm_out) and
// exports head-7 combined m,l for att_kernel.
// ---------------------------------------------------------------------------
__global__ __launch_bounds__(256)
void combine_kernel(const float* __restrict__ Opart,
                    const float* __restrict__ mPart, const float* __restrict__ lPart,
                    __bf16* __restrict__ yhi, __bf16* __restrict__ ylo,
                    float* __restrict__ mM, float* __restrict__ lL) {
    int idx = blockIdx.x * 256 + threadIdx.x;   // one float4 of y per thread
    int t = idx >> 8;
    int c4 = idx & 255;
    int c = c4 * 4;
    int h = c >> 7;
    float m0 = mPart[(size_t)h * Tn + t];
    float m1 = mPart[(size_t)(Hn + h) * Tn + t];
    float l0 = lPart[(size_t)h * Tn + t];
    float l1 = lPart[(size_t)(Hn + h) * Tn + t];
    float m = fmaxf(m0, m1);
    float w0 = exp2f((m0 - m) * LOG2E);
    float w1 = exp2f((m1 - m) * LOG2E);
    float l = l0 * w0 + l1 * w1;
    float inv = 1.0f / l;
    w0 *= inv; w1 *= inv;
    float4 a = ((const float4*)Opart)[idx];
    float4 b = ((const float4*)(Opart + (size_t)Tn * Dm))[idx];
    float y[4] = {a.x * w0 + b.x * w1, a.y * w0 + b.y * w1,
                  a.z * w0 + b.z * w1, a.w * w0 + b.w * w1};
    __attribute__((aligned(8))) __bf16 hh[4], ll[4];
#pragma unroll
    for (int j = 0; j < 4; ++j) {
        hh[j] = (__bf16)y[j];
        ll[j] = (__bf16)(y[j] - (float)hh[j]);
    }
    *(float2*)&yhi[(size_t)idx * 4] = *(float2*)hh;
    *(float2*)&ylo[(size_t)idx * 4] = *(float2*)ll;
    if (h == 7 && (c & 127) == 0) { mM[t] = m; lL[t] = l; }
}

// ---------------------------------------------------------------------------
// att[-1] regeneration: S7 = Q7 K7^T (3-pass) + bias, att = exp2((S-m)lg2e)/l,
// stored via LDS-staged coalesced epilogue (two 64-col phases).
// ---------------------------------------------------------------------------
__global__ __launch_bounds__(256)
void att_kernel(const __bf16* __restrict__ Ahi, const __bf16* __restrict__ Alo,
                const __bf16* __restrict__ Bhi, const __bf16* __restrict__ Blo,
                const float* __restrict__ mM, const float* __restrict__ lL,
                float* __restrict__ att) {
    __shared__ __align__(16) char shraw[34816];  // max(32768 gemm, 34816 Ls)
    __bf16 (*smem)[128 * 32] = reinterpret_cast<__bf16(*)[128 * 32]>(shraw);
    float (*Ls)[68] = reinterpret_cast<float(*)[68]>(shraw);

    int m0 = blockIdx.y * 128, n0 = blockIdx.x * 128;
    int tid = threadIdx.x, lane = tid & 63, wid = tid >> 6;
    int wm = (wid >> 1) * 64, wn = (wid & 1) * 64;
    int lm = lane & 15, q = lane >> 4;
    f32x4 acc[4][4];
#pragma unroll
    for (int i = 0; i < 4; ++i)
#pragma unroll
        for (int j = 0; j < 4; ++j) acc[i][j] = (f32x4){0.f, 0.f, 0.f, 0.f};
    gemm_body(smem, Ahi, Alo, Bhi, Blo, DH, DH, DH, m0, n0, acc);

    // normalize in-register
    float wv[4];
#pragma unroll
    for (int nt = 0; nt < 4; ++nt) {
        int s = n0 + wn + nt * 16 + lm;
        wv[nt] = exp2f(-(float)(s >> 1) * WEXP);
    }
    int par = lm & 1;
#pragma unroll
    for (int mt = 0; mt < 4; ++mt)
#pragma unroll
        for (int r = 0; r < 4; ++r) {
            int t = m0 + wm + mt * 16 + q * 4 + r;
            float tf = (float)t;
            float mr = mM[t];
            float linv = 1.0f / lL[t];
#pragma unroll
            for (int nt = 0; nt < 4; ++nt) {
                float ang = tf * wv[nt];
                float bias = __sinf(par ? ang + PIO2 : ang);  // cos = sin(+pi/2)
                acc[mt][nt][r] = exp2f((acc[mt][nt][r] + bias - mr) * LOG2E) * linv;
            }
        }

    // two-phase LDS-staged coalesced store (cols wn = p*64)
#pragma unroll
    for (int p = 0; p < 2; ++p) {
        __syncthreads();
        if ((wid & 1) == p) {
#pragma unroll
            for (int mt = 0; mt < 4; ++mt)
#pragma unroll
                for (int r = 0; r < 4; ++r)
#pragma unroll
                    for (int nt = 0; nt < 4; ++nt)
                        Ls[wm + mt * 16 + q * 4 + r][nt * 16 + lm] = acc[mt][nt][r];
        }
        __syncthreads();
#pragma unroll
        for (int j = 0; j < 8; ++j) {
            int row = j * 16 + (tid >> 4);
            int col = (tid & 15) * 4;
            float4 v = *(float4*)&Ls[row][col];
            *(float4*)&att[(size_t)(m0 + row) * Tn + n0 + p * 64 + col] = v;
        }
    }
}

// ---------------------------------------------------------------------------
extern "C" void kernel_launch(void* const* d_in, const int* in_sizes, int n_in,
                              void* d_out, int out_size, void* d_ws, size_t ws_size,
                              hipStream_t stream) {
    (void)in_sizes; (void)n_in; (void)out_size; (void)ws_size;
    const float* x    = (const float*)d_in[0];
    const float* Wq   = (const float*)d_in[1];
    const float* Wk   = (const float*)d_in[2];
    const float* Wv   = (const float*)d_in[3];
    const float* Wout = (const float*)d_in[4];

    float* out_y   = (float*)d_out;              // [4096][1024]
    float* out_att = out_y + (size_t)Tn * Dm;    // [4096][4096]

    const size_t MB = 1ull << 20;
    char* W = (char*)d_ws;
    __bf16* xhi  = (__bf16*)(W + 0 * MB);
    __bf16* xlo  = (__bf16*)(W + 8 * MB);
    __bf16* Wqhi = (__bf16*)(W + 16 * MB);
    __bf16* Wqlo = (__bf16*)(W + 18 * MB);
    __bf16* Wkhi = (__bf16*)(W + 20 * MB);
    __bf16* Wklo = (__bf16*)(W + 22 * MB);
    __bf16* Wvhi = (__bf16*)(W + 24 * MB);
    __bf16* Wvlo = (__bf16*)(W + 26 * MB);
    __bf16* Wohi = (__bf16*)(W + 28 * MB);
    __bf16* Wolo = (__bf16*)(W + 30 * MB);
    __bf16* Qhi  = (__bf16*)(W + 32 * MB);   // [H][T][DH]
    __bf16* Qlo  = (__bf16*)(W + 40 * MB);
    __bf16* Khi  = (__bf16*)(W + 48 * MB);
    __bf16* Klo  = (__bf16*)(W + 56 * MB);
    __bf16* Vb   = (__bf16*)(W + 64 * MB);   // [H][T][DH]
    __bf16* Vt   = (__bf16*)(W + 72 * MB);   // [H][DH][T]
    float*  mM    = (float*)(W + 80 * MB);   // [T]
    float*  lL    = (float*)(W + 81 * MB);   // [T]
    float*  mPart = (float*)(W + 82 * MB);   // [2][H][T]
    float*  lPart = (float*)(W + 83 * MB);   // [2][H][T]
    float*  Opart = (float*)(W + 84 * MB);   // [2][T][1024] fp32 (32 MB)
    __bf16* yhhi  = (__bf16*)(W + 116 * MB); // [T][1024] bf16
    __bf16* yhlo  = (__bf16*)(W + 124 * MB);

    dim3 blk(256);

    split_kernel<<<dim3(Tn * Dm / 4 / 256), blk, 0, stream>>>(x, xhi, xlo, Tn * Dm / 4);
    split_kernel<<<dim3(Dm * Dm / 4 / 256), blk, 0, stream>>>(Wq, Wqhi, Wqlo, Dm * Dm / 4);
    split_kernel<<<dim3(Dm * Dm / 4 / 256), blk, 0, stream>>>(Wk, Wkhi, Wklo, Dm * Dm / 4);
    split_kernel<<<dim3(Dm * Dm / 4 / 256), blk, 0, stream>>>(Wv, Wvhi, Wvlo, Dm * Dm / 4);
    split_kernel<<<dim3(Dm * Dm / 4 / 256), blk, 0, stream>>>(Wout, Wohi, Wolo, Dm * Dm / 4);

    // fused QKV projection (z: 0=Q split, 1=K split, 2=V plain)
    qkv_kernel<<<dim3(Dm / 128, Tn / 128, 3), blk, 0, stream>>>(
        xhi, xlo, Wqhi, Wqlo, Wkhi, Wklo, Wvhi, Wvlo,
        Qhi, Qlo, Khi, Klo, Vb);
    vtrans_kernel<<<dim3(Tn / 64, DH / 64, Hn), blk, 0, stream>>>(Vb, Vt);

    // flash attention v8 (frozen, 351 us)
    flash_kernel<<<dim3(1024), blk, 0, stream>>>(Qhi, Qlo, Khi, Klo, Vt,
                                                 Opart, mPart, lPart);

    // merge KV halves -> y (bf16 hi/lo) + head-7 m,l
    combine_kernel<<<dim3(Tn * Dm / 4 / 256), blk, 0, stream>>>(
        Opart, mPart, lPart, yhhi, yhlo, mM, lL);

    // att[-1] regeneration from head-7 m,l
    const size_t TD = (size_t)Tn * DH;
    att_kernel<<<dim3(Tn / 128, Tn / 128), blk, 0, stream>>>(
        Qhi + 7 * TD, Qlo + 7 * TD, Khi + 7 * TD, Klo + 7 * TD, mM, lL, out_att);

    // output projection
    gemm_out<<<dim3(Dm / 128, Tn / 128), blk, 0, stream>>>(yhhi, yhlo, Wohi, Wolo, out_y);
}

// Round 11
// 568.299 us; speedup vs baseline: 1.0749x; 1.0175x over previous
//
#include <hip/hip_runtime.h>
#include <math.h>

#define Tn 4096
#define Dm 1024
#define Hn 8
#define DH 128

typedef __bf16 bf16x8 __attribute__((ext_vector_type(8)));
typedef float f32x4 __attribute__((ext_vector_type(4)));

#define LOG2E 1.4426950408889634f
#define WEXP 0.025952563241307518f  // log2(10000)/512
#define WDECAY 0.31622776601683794f // 10000^(-128/1024): angle decay per 128-col KV tile
#define PIO2 1.5707963267948966f

#define MFMA(a, b, c) __builtin_amdgcn_mfma_f32_16x16x32_bf16((a), (b), (c), 0, 0, 0)

// async global->LDS 16B per lane; dest is wave-uniform base + lane*16
#define GLOAD_LDS(g, l) __builtin_amdgcn_global_load_lds( \
    (__attribute__((address_space(1))) void*)(void*)(g),  \
    (__attribute__((address_space(3))) void*)(l), 16, 0, 0)

// ---------------------------------------------------------------------------
// fp32 -> (hi, lo) bf16 split
__global__ __launch_bounds__(256)
void split_kernel(const float* __restrict__ in, __bf16* __restrict__ hi,
                  __bf16* __restrict__ lo, int n4) {
    int idx = blockIdx.x * 256 + threadIdx.x;
    if (idx >= n4) return;
    float4 v = ((const float4*)in)[idx];
    __attribute__((aligned(8))) __bf16 h[4], l[4];
    h[0] = (__bf16)v.x; h[1] = (__bf16)v.y; h[2] = (__bf16)v.z; h[3] = (__bf16)v.w;
    l[0] = (__bf16)(v.x - (float)h[0]);
    l[1] = (__bf16)(v.y - (float)h[1]);
    l[2] = (__bf16)(v.z - (float)h[2]);
    l[3] = (__bf16)(v.w - (float)h[3]);
    *(float2*)&hi[(size_t)idx * 4] = *(float2*)h;
    *(float2*)&lo[(size_t)idx * 4] = *(float2*)l;
}

// V[h][t][e] bf16 -> Vt[h][e][t] bf16
__global__ __launch_bounds__(256)
void vtrans_kernel(const __bf16* __restrict__ V, __bf16* __restrict__ Vt) {
    __shared__ __bf16 tile[64][80];
    int h = blockIdx.z, t0 = blockIdx.x * 64, e0 = blockIdx.y * 64;
    const __bf16* Vh = V + (size_t)h * Tn * DH;
    __bf16* Vth = Vt + (size_t)h * DH * Tn;
#pragma unroll
    for (int p = 0; p < 2; ++p) {
        int r = (threadIdx.x >> 3) + p * 32;
        int c = (threadIdx.x & 7) * 8;
        *(float4*)&tile[r][c] = *(const float4*)&Vh[(size_t)(t0 + r) * DH + e0 + c];
    }
    __syncthreads();
#pragma unroll
    for (int p = 0; p < 2; ++p) {
        int r = (threadIdx.x >> 3) + p * 32;
        int c = (threadIdx.x & 7) * 8;
        __attribute__((aligned(16))) __bf16 tmp[8];
#pragma unroll
        for (int j = 0; j < 8; ++j) tmp[j] = tile[c + j][r];
        *(float4*)&Vth[(size_t)(e0 + r) * Tn + t0 + c] = *(float4*)tmp;
    }
}

// ---------------------------------------------------------------------------
// Shared 128x128-tile NT GEMM body (BK=32, 4 waves 2x2, optional hi/lo 3-pass)
// global_load_lds width-16 staging into LINEAR [128][32] bf16 tiles.
// ---------------------------------------------------------------------------
__device__ __forceinline__
void gemm_body(__bf16 (*smem)[128 * 32],
               const __bf16* __restrict__ Ahi, const __bf16* __restrict__ Alo,
               const __bf16* __restrict__ Bhi, const __bf16* __restrict__ Blo,
               int ldA, int ldB, int K, int m0, int n0, f32x4 acc[4][4]) {
    int tid = threadIdx.x;
    int lane = tid & 63, wid = tid >> 6;
    int wm = (wid >> 1) * 64, wn = (wid & 1) * 64;
    int lm = lane & 15, q = lane >> 4;
    int lr = lane >> 2;          // row within 16-row chunk
    int lc = (lane & 3) * 8;     // col (bf16 units)
    const bool split = (Alo != nullptr);
    for (int k0 = 0; k0 < K; k0 += 32) {
        __syncthreads();
#pragma unroll
        for (int p = 0; p < 128; p += 64) {
            int rb = p + wid * 16;           // wave-uniform chunk base row
            int r = rb + lr;                 // per-lane global row
            GLOAD_LDS(&Ahi[(size_t)(m0 + r) * ldA + k0 + lc], &smem[0][rb * 32]);
            GLOAD_LDS(&Bhi[(size_t)(n0 + r) * ldB + k0 + lc], &smem[2][rb * 32]);
            if (split) {
                GLOAD_LDS(&Alo[(size_t)(m0 + r) * ldA + k0 + lc], &smem[1][rb * 32]);
                GLOAD_LDS(&Blo[(size_t)(n0 + r) * ldB + k0 + lc], &smem[3][rb * 32]);
            }
        }
        __syncthreads();
        bf16x8 ah[4], bh[4], al[4], bl[4];
#pragma unroll
        for (int mt = 0; mt < 4; ++mt) {
            ah[mt] = *(const bf16x8*)&smem[0][(wm + mt * 16 + lm) * 32 + q * 8];
            if (split)
                al[mt] = *(const bf16x8*)&smem[1][(wm + mt * 16 + lm) * 32 + q * 8];
        }
#pragma unroll
        for (int nt = 0; nt < 4; ++nt) {
            bh[nt] = *(const bf16x8*)&smem[2][(wn + nt * 16 + lm) * 32 + q * 8];
            if (split)
                bl[nt] = *(const bf16x8*)&smem[3][(wn + nt * 16 + lm) * 32 + q * 8];
        }
#pragma unroll
        for (int mt = 0; mt < 4; ++mt)
#pragma unroll
            for (int nt = 0; nt < 4; ++nt) {
                acc[mt][nt] = MFMA(ah[mt], bh[nt], acc[mt][nt]);
                if (split) {
                    acc[mt][nt] = MFMA(ah[mt], bl[nt], acc[mt][nt]);
                    acc[mt][nt] = MFMA(al[mt], bh[nt], acc[mt][nt]);
                }
            }
    }
}

// ---------------------------------------------------------------------------
// Fused QKV projection: blockIdx.z selects Q/K/V. Output in [h][t][e] layout,
// Q/K split hi/lo, V plain bf16. Direct-store epilogue (r8-proven).
// ---------------------------------------------------------------------------
__global__ __launch_bounds__(256)
void qkv_kernel(const __bf16* __restrict__ xhi, const __bf16* __restrict__ xlo,
                const __bf16* __restrict__ Wqh, const __bf16* __restrict__ Wql,
                const __bf16* __restrict__ Wkh, const __bf16* __restrict__ Wkl,
                const __bf16* __restrict__ Wvh, const __bf16* __restrict__ Wvl,
                __bf16* __restrict__ Qh, __bf16* __restrict__ Ql,
                __bf16* __restrict__ Kh, __bf16* __restrict__ Kl,
                __bf16* __restrict__ Vb) {
    __shared__ __align__(16) __bf16 smem[4][128 * 32];   // 32 KB
    int z = blockIdx.z;
    const __bf16* Bh = (z == 0) ? Wqh : (z == 1) ? Wkh : Wvh;
    const __bf16* Bl = (z == 0) ? Wql : (z == 1) ? Wkl : Wvl;
    __bf16* Oh = (z == 0) ? Qh : (z == 1) ? Kh : Vb;
    __bf16* Ol = (z == 0) ? Ql : (z == 1) ? Kl : nullptr;
    int m0 = blockIdx.y * 128, n0 = blockIdx.x * 128;
    int tid = threadIdx.x, lane = tid & 63, wid = tid >> 6;
    int wm = (wid >> 1) * 64, wn = (wid & 1) * 64;
    int lm = lane & 15, q = lane >> 4;
    f32x4 acc[4][4];
#pragma unroll
    for (int i = 0; i < 4; ++i)
#pragma unroll
        for (int j = 0; j < 4; ++j) acc[i][j] = (f32x4){0.f, 0.f, 0.f, 0.f};
    gemm_body(smem, xhi, xlo, Bh, Bl, Dm, Dm, Dm, m0, n0, acc);
#pragma unroll
    for (int mt = 0; mt < 4; ++mt)
#pragma unroll
        for (int r = 0; r < 4; ++r) {
            int grow = m0 + wm + mt * 16 + q * 4 + r;
#pragma unroll
            for (int nt = 0; nt < 4; ++nt) {
                int gc = n0 + wn + nt * 16 + lm;
                int h = gc >> 7, e = gc & 127;
                size_t o = ((size_t)h * Tn + grow) * DH + e;
                float v = acc[mt][nt][r];
                __bf16 hv = (__bf16)v;
                Oh[o] = hv;
                if (Ol) Ol[o] = (__bf16)(v - (float)hv);
            }
        }
}

// ---------------------------------------------------------------------------
// Output projection: C = A B^T fp32 store
// ---------------------------------------------------------------------------
__global__ __launch_bounds__(256)
void gemm_out(const __bf16* __restrict__ Ahi, const __bf16* __restrict__ Alo,
              const __bf16* __restrict__ Bhi, const __bf16* __restrict__ Blo,
              float* __restrict__ C) {
    __shared__ __align__(16) __bf16 smem[4][128 * 32];   // 32 KB
    int m0 = blockIdx.y * 128, n0 = blockIdx.x * 128;
    int tid = threadIdx.x, lane = tid & 63, wid = tid >> 6;
    int wm = (wid >> 1) * 64, wn = (wid & 1) * 64;
    int lm = lane & 15, q = lane >> 4;
    f32x4 acc[4][4];
#pragma unroll
    for (int i = 0; i < 4; ++i)
#pragma unroll
        for (int j = 0; j < 4; ++j) acc[i][j] = (f32x4){0.f, 0.f, 0.f, 0.f};
    gemm_body(smem, Ahi, Alo, Bhi, Blo, Dm, Dm, Dm, m0, n0, acc);
#pragma unroll
    for (int mt = 0; mt < 4; ++mt)
#pragma unroll
        for (int r = 0; r < 4; ++r) {
            int grow = m0 + wm + mt * 16 + q * 4 + r;
#pragma unroll
            for (int nt = 0; nt < 4; ++nt)
                C[(size_t)grow * Dm + n0 + wn + nt * 16 + lm] = acc[mt][nt][r];
        }
}

// ---------------------------------------------------------------------------
// Flash attention v9 = v8 pipeline (depth-2 K relay, intra-wave Ps, V relay,
// setprio) + UNSPLIT KV + T13 defer-max.
//  - Unsplit: 512 blocks x 32 KV tiles. Occupancy is reg-pinned at 2
//    blocks/CU either way (r2-r4 ladder), so KV-split-2 bought nothing but
//    cost 32MB fp32 Opart + the 48MB combine round-trip. Flash now
//    normalizes in-register and writes yhhi/yhlo bf16 directly; head 7
//    exports m,l. combine_kernel deleted.
//  - T13 defer-max (THR=8 nat-log units): skip max-update+alpha rescale when
//    rmax <= mrow+8 for all rows (P bounded by e^8; bf16 P has relative
//    precision and l carries the same scale, so normalization cancels).
//    Removes 4 exp2 + 32 accO mults from the PV critical path on ~every tile.
// ---------------------------------------------------------------------------
#define QK_STEP(SET, BUF, QIDX, NIT, NKC)                                     \
    {                                                                          \
        *(float4*)&Ks[BUF][0][sr][scc]      = SET##h0;                         \
        *(float4*)&Ks[BUF][1][sr][scc]      = SET##l0;                         \
        *(float4*)&Ks[BUF][0][sr + 64][scc] = SET##h1;                         \
        *(float4*)&Ks[BUF][1][sr + 64][scc] = SET##l1;                         \
        __syncthreads();                                                       \
        {                                                                      \
            size_t go0 = (size_t)((NIT) * 128 + sr) * DH + (NKC) * 32 + scc;   \
            size_t go1 = go0 + (size_t)64 * DH;                                \
            SET##h0 = *(const float4*)&Kh[go0];                                \
            SET##l0 = *(const float4*)&Kl[go0];                                \
            SET##h1 = *(const float4*)&Kh[go1];                                \
            SET##l1 = *(const float4*)&Kl[go1];                                \
        }                                                                      \
        __builtin_amdgcn_s_setprio(1);                                         \
        _Pragma("unroll")                                                      \
        for (int nt = 0; nt < 8; ++nt) {                                       \
            bf16x8 kbh = *(const bf16x8*)&Ks[BUF][0][nt * 16 + lm][q * 8];     \
            bf16x8 kbl = *(const bf16x8*)&Ks[BUF][1][nt * 16 + lm][q * 8];     \
            accS[nt] = MFMA(qfh[QIDX], kbh, accS[nt]);                         \
            accS[nt] = MFMA(qfh[QIDX], kbl, accS[nt]);                         \
            accS[nt] = MFMA(qfl[QIDX], kbh, accS[nt]);                         \
        }                                                                      \
        __builtin_amdgcn_s_setprio(0);                                         \
    }

__global__ __launch_bounds__(256, 2)
void flash_kernel(const __bf16* __restrict__ Qhi, const __bf16* __restrict__ Qlo,
                  const __bf16* __restrict__ Khi, const __bf16* __restrict__ Klo,
                  const __bf16* __restrict__ Vt,
                  __bf16* __restrict__ yhi, __bf16* __restrict__ ylo,
                  float* __restrict__ mM, float* __restrict__ lL) {
    __shared__ __bf16 Ks[2][2][128][40];  // 40960 B  [buf][hi/lo][row][col]
    __shared__ __bf16 Ps[64][132];        // 16896 B
    int bid = blockIdx.x;
    int h = bid & 7;
    int m0 = (bid >> 3) * 64;
    const size_t TD = (size_t)Tn * DH;
    const __bf16* Qh = Qhi + h * TD;
    const __bf16* Ql = Qlo + h * TD;
    const __bf16* Kh = Khi + h * TD;
    const __bf16* Kl = Klo + h * TD;
    const __bf16* Vh = Vt + h * TD;

    int tid = threadIdx.x;
    int lane = tid & 63, wid = tid >> 6;
    int lm = lane & 15, q = lane >> 4;
    int wr0 = wid * 16;

    // Q fragments in registers (hi + lo)
    bf16x8 qfh[4], qfl[4];
#pragma unroll
    for (int kc = 0; kc < 4; ++kc) {
        size_t o = (size_t)(m0 + wr0 + lm) * DH + kc * 32 + q * 8;
        qfh[kc] = *(const bf16x8*)&Qh[o];
        qfl[kc] = *(const bf16x8*)&Ql[o];
    }

    f32x4 accO[8];
#pragma unroll
    for (int nt = 0; nt < 8; ++nt) accO[nt] = (f32x4){0.f, 0.f, 0.f, 0.f};
    float mrow[4], lrow[4];
#pragma unroll
    for (int r = 0; r < 4; ++r) { mrow[r] = -3.0e38f; lrow[r] = 0.f; }

    int sr = tid >> 2;
    int scc = (tid & 3) * 8;
    bool iscos = (lm & 1);
    float wv[8];
#pragma unroll
    for (int nt = 0; nt < 8; ++nt)
        wv[nt] = exp2f(-(float)((nt * 16 + lm) >> 1) * WEXP);
    float tf[4];
#pragma unroll
    for (int r = 0; r < 4; ++r) tf[r] = (float)(m0 + wr0 + q * 4 + r);

    // V fragment base offsets (per nt row; col advances with s0/kc)
    size_t voff[8];
#pragma unroll
    for (int nt = 0; nt < 8; ++nt)
        voff[nt] = (size_t)(nt * 16 + lm) * Tn + q * 8;

    // depth-2 K staging relay: set ka holds even-kc chunks, kb odd-kc chunks
    float4 kah0, kal0, kah1, kal1, kbh0, kbl0, kbh1, kbl1;
    {
        size_t g0 = (size_t)sr * DH + scc;                   // (it=0, kc=0)
        size_t g1 = g0 + (size_t)64 * DH;
        kah0 = *(const float4*)&Kh[g0]; kal0 = *(const float4*)&Kl[g0];
        kah1 = *(const float4*)&Kh[g1]; kal1 = *(const float4*)&Kl[g1];
        size_t h0_ = g0 + 32, h1_ = g1 + 32;                 // (it=0, kc=1)
        kbh0 = *(const float4*)&Kh[h0_]; kbl0 = *(const float4*)&Kl[h0_];
        kbh1 = *(const float4*)&Kh[h1_]; kbl1 = *(const float4*)&Kl[h1_];
    }

    for (int it = 0; it < 32; ++it) {
        int s0 = it * 128;
        int itn = (it < 31) ? it + 1 : it;
        f32x4 accS[8];
#pragma unroll
        for (int nt = 0; nt < 8; ++nt) accS[nt] = (f32x4){0.f, 0.f, 0.f, 0.f};

        // ---- S = Q K^T: 4 kc steps, depth-2 relay ----
        QK_STEP(ka, 0, 0, it, 2)      // commit (it,0); load (it,2)
        QK_STEP(kb, 1, 1, it, 3)      // commit (it,1); load (it,3)
        QK_STEP(ka, 0, 2, itn, 0)     // commit (it,2); load (it+1,0)
        QK_STEP(kb, 1, 3, itn, 1)     // commit (it,3); load (it+1,1)

        // ---- prefetch V kc=0 frags; latency hides under the softmax ----
        bf16x8 vrel[8];
#pragma unroll
        for (int nt = 0; nt < 8; ++nt)
            vrel[nt] = *(const bf16x8*)&Vh[voff[nt] + s0];

        // ---- bias + online softmax, T13 defer-max ----
        float rmax[4];
#pragma unroll
        for (int r = 0; r < 4; ++r) {
            float mx = -3.0e38f;
#pragma unroll
            for (int nt = 0; nt < 8; ++nt) {
                float ang = tf[r] * wv[nt];
                float b = __sinf(iscos ? ang + PIO2 : ang);  // cos(x)=sin(x+pi/2)
                float v = accS[nt][r] + b;
                accS[nt][r] = v;
                mx = fmaxf(mx, v);
            }
            rmax[r] = mx;
        }
#pragma unroll
        for (int off = 1; off < 16; off <<= 1)
#pragma unroll
            for (int r = 0; r < 4; ++r)
                rmax[r] = fmaxf(rmax[r], __shfl_xor(rmax[r], off));
        // defer-max: rescale only if some row's max grew past THR=8 (nat-log)
        bool need = (rmax[0] > mrow[0] + 8.0f) || (rmax[1] > mrow[1] + 8.0f) ||
                    (rmax[2] > mrow[2] + 8.0f) || (rmax[3] > mrow[3] + 8.0f);
        if (__any(need)) {
            float alpha[4];
#pragma unroll
            for (int r = 0; r < 4; ++r) {
                float mn = fmaxf(mrow[r], rmax[r]);
                alpha[r] = exp2f((mrow[r] - mn) * LOG2E);
                mrow[r] = mn;
                lrow[r] *= alpha[r];
            }
#pragma unroll
            for (int nt = 0; nt < 8; ++nt)
#pragma unroll
                for (int r = 0; r < 4; ++r)
                    accO[nt][r] *= alpha[r];
        }
        float rsum[4];
#pragma unroll
        for (int r = 0; r < 4; ++r) rsum[r] = 0.f;
#pragma unroll
        for (int nt = 0; nt < 8; ++nt)
#pragma unroll
            for (int r = 0; r < 4; ++r) {
                float p = exp2f((accS[nt][r] - mrow[r]) * LOG2E);
                accS[nt][r] = p;
                rsum[r] += p;
            }
#pragma unroll
        for (int off = 1; off < 16; off <<= 1)
#pragma unroll
            for (int r = 0; r < 4; ++r)
                rsum[r] += __shfl_xor(rsum[r], off);
#pragma unroll
        for (int r = 0; r < 4; ++r)
            lrow[r] += rsum[r];

        // ---- P relayout via LDS (intra-wave rows wr0..wr0+15; no barrier) ----
#pragma unroll
        for (int nt = 0; nt < 8; ++nt)
#pragma unroll
            for (int r = 0; r < 4; ++r)
                Ps[wr0 + q * 4 + r][nt * 16 + lm] = (__bf16)accS[nt][r];

        // ---- O += P @ V (V frags via register relay: use kc, fetch kc+1) ----
#pragma unroll
        for (int kc = 0; kc < 4; ++kc) {
            bf16x8 pa = *(const bf16x8*)&Ps[wr0 + lm][kc * 32 + q * 8];
            bf16x8 vcur[8];
#pragma unroll
            for (int nt = 0; nt < 8; ++nt) vcur[nt] = vrel[nt];
            if (kc < 3) {
#pragma unroll
                for (int nt = 0; nt < 8; ++nt)
                    vrel[nt] = *(const bf16x8*)&Vh[voff[nt] + s0 + (kc + 1) * 32];
            }
            __builtin_amdgcn_s_setprio(1);
#pragma unroll
            for (int nt = 0; nt < 8; ++nt)
                accO[nt] = MFMA(pa, vcur[nt], accO[nt]);
            __builtin_amdgcn_s_setprio(0);
        }

        // advance bias frequencies to next 128-col tile
#pragma unroll
        for (int nt = 0; nt < 8; ++nt) wv[nt] *= WDECAY;
    }

    // ---- epilogue: normalize in-register, write y bf16 hi/lo + head-7 m,l ----
#pragma unroll
    for (int r = 0; r < 4; ++r) {
        float inv = 1.0f / lrow[r];
        int t = m0 + wr0 + q * 4 + r;
#pragma unroll
        for (int nt = 0; nt < 8; ++nt) {
            float v = accO[nt][r] * inv;
            __bf16 hv = (__bf16)v;
            size_t o = (size_t)t * Dm + h * DH + nt * 16 + lm;
            yhi[o] = hv;
            ylo[o] = (__bf16)(v - (float)hv);
        }
        if (h == 7 && lm == 0) {
            mM[t] = mrow[r];
            lL[t] = lrow[r];
        }
    }
}

// ---------------------------------------------------------------------------
// att[-1] regeneration: S7 = Q7 K7^T (3-pass) + bias, att = exp2((S-m)lg2e)/l,
// stored via LDS-staged coalesced epilogue (two 64-col phases).
// ---------------------------------------------------------------------------
__global__ __launch_bounds__(256)
void att_kernel(const __bf16* __restrict__ Ahi, const __bf16* __restrict__ Alo,
                const __bf16* __restrict__ Bhi, const __bf16* __restrict__ Blo,
                const float* __restrict__ mM, const float* __restrict__ lL,
                float* __restrict__ att) {
    __shared__ __align__(16) char shraw[34816];  // max(32768 gemm, 34816 Ls)
    __bf16 (*smem)[128 * 32] = reinterpret_cast<__bf16(*)[128 * 32]>(shraw);
    float (*Ls)[68] = reinterpret_cast<float(*)[68]>(shraw);

    int m0 = blockIdx.y * 128, n0 = blockIdx.x * 128;
    int tid = threadIdx.x, lane = tid & 63, wid = tid >> 6;
    int wm = (wid >> 1) * 64, wn = (wid & 1) * 64;
    int lm = lane & 15, q = lane >> 4;
    f32x4 acc[4][4];
#pragma unroll
    for (int i = 0; i < 4; ++i)
#pragma unroll
        for (int j = 0; j < 4; ++j) acc[i][j] = (f32x4){0.f, 0.f, 0.f, 0.f};
    gemm_body(smem, Ahi, Alo, Bhi, Blo, DH, DH, DH, m0, n0, acc);

    // normalize in-register
    float wv[4];
#pragma unroll
    for (int nt = 0; nt < 4; ++nt) {
        int s = n0 + wn + nt * 16 + lm;
        wv[nt] = exp2f(-(float)(s >> 1) * WEXP);
    }
    int par = lm & 1;
#pragma unroll
    for (int mt = 0; mt < 4; ++mt)
#pragma unroll
        for (int r = 0; r < 4; ++r) {
            int t = m0 + wm + mt * 16 + q * 4 + r;
            float tf = (float)t;
            float mr = mM[t];
            float linv = 1.0f / lL[t];
#pragma unroll
            for (int nt = 0; nt < 4; ++nt) {
                float ang = tf * wv[nt];
                float bias = __sinf(par ? ang + PIO2 : ang);  // cos = sin(+pi/2)
                acc[mt][nt][r] = exp2f((acc[mt][nt][r] + bias - mr) * LOG2E) * linv;
            }
        }

    // two-phase LDS-staged coalesced store (cols wn = p*64)
#pragma unroll
    for (int p = 0; p < 2; ++p) {
        __syncthreads();
        if ((wid & 1) == p) {
#pragma unroll
            for (int mt = 0; mt < 4; ++mt)
#pragma unroll
                for (int r = 0; r < 4; ++r)
#pragma unroll
                    for (int nt = 0; nt < 4; ++nt)
                        Ls[wm + mt * 16 + q * 4 + r][nt * 16 + lm] = acc[mt][nt][r];
        }
        __syncthreads();
#pragma unroll
        for (int j = 0; j < 8; ++j) {
            int row = j * 16 + (tid >> 4);
            int col = (tid & 15) * 4;
            float4 v = *(float4*)&Ls[row][col];
            *(float4*)&att[(size_t)(m0 + row) * Tn + n0 + p * 64 + col] = v;
        }
    }
}

// ---------------------------------------------------------------------------
extern "C" void kernel_launch(void* const* d_in, const int* in_sizes, int n_in,
                              void* d_out, int out_size, void* d_ws, size_t ws_size,
                              hipStream_t stream) {
    (void)in_sizes; (void)n_in; (void)out_size; (void)ws_size;
    const float* x    = (const float*)d_in[0];
    const float* Wq   = (const float*)d_in[1];
    const float* Wk   = (const float*)d_in[2];
    const float* Wv   = (const float*)d_in[3];
    const float* Wout = (const float*)d_in[4];

    float* out_y   = (float*)d_out;              // [4096][1024]
    float* out_att = out_y + (size_t)Tn * Dm;    // [4096][4096]

    const size_t MB = 1ull << 20;
    char* W = (char*)d_ws;
    __bf16* xhi  = (__bf16*)(W + 0 * MB);
    __bf16* xlo  = (__bf16*)(W + 8 * MB);
    __bf16* Wqhi = (__bf16*)(W + 16 * MB);
    __bf16* Wqlo = (__bf16*)(W + 18 * MB);
    __bf16* Wkhi = (__bf16*)(W + 20 * MB);
    __bf16* Wklo = (__bf16*)(W + 22 * MB);
    __bf16* Wvhi = (__bf16*)(W + 24 * MB);
    __bf16* Wvlo = (__bf16*)(W + 26 * MB);
    __bf16* Wohi = (__bf16*)(W + 28 * MB);
    __bf16* Wolo = (__bf16*)(W + 30 * MB);
    __bf16* Qhi  = (__bf16*)(W + 32 * MB);   // [H][T][DH]
    __bf16* Qlo  = (__bf16*)(W + 40 * MB);
    __bf16* Khi  = (__bf16*)(W + 48 * MB);
    __bf16* Klo  = (__bf16*)(W + 56 * MB);
    __bf16* Vb   = (__bf16*)(W + 64 * MB);   // [H][T][DH]
    __bf16* Vt   = (__bf16*)(W + 72 * MB);   // [H][DH][T]
    float*  mM   = (float*)(W + 80 * MB);    // [T]
    float*  lL   = (float*)(W + 81 * MB);    // [T]
    __bf16* yhhi = (__bf16*)(W + 116 * MB);  // [T][1024] bf16
    __bf16* yhlo = (__bf16*)(W + 124 * MB);

    dim3 blk(256);

    split_kernel<<<dim3(Tn * Dm / 4 / 256), blk, 0, stream>>>(x, xhi, xlo, Tn * Dm / 4);
    split_kernel<<<dim3(Dm * Dm / 4 / 256), blk, 0, stream>>>(Wq, Wqhi, Wqlo, Dm * Dm / 4);
    split_kernel<<<dim3(Dm * Dm / 4 / 256), blk, 0, stream>>>(Wk, Wkhi, Wklo, Dm * Dm / 4);
    split_kernel<<<dim3(Dm * Dm / 4 / 256), blk, 0, stream>>>(Wv, Wvhi, Wvlo, Dm * Dm / 4);
    split_kernel<<<dim3(Dm * Dm / 4 / 256), blk, 0, stream>>>(Wout, Wohi, Wolo, Dm * Dm / 4);

    // fused QKV projection (z: 0=Q split, 1=K split, 2=V plain)
    qkv_kernel<<<dim3(Dm / 128, Tn / 128, 3), blk, 0, stream>>>(
        xhi, xlo, Wqhi, Wqlo, Wkhi, Wklo, Wvhi, Wvlo,
        Qhi, Qlo, Khi, Klo, Vb);
    vtrans_kernel<<<dim3(Tn / 64, DH / 64, Hn), blk, 0, stream>>>(Vb, Vt);

    // flash attention v9: unsplit KV, direct bf16 y output, defer-max
    flash_kernel<<<dim3(512), blk, 0, stream>>>(Qhi, Qlo, Khi, Klo, Vt,
                                                yhhi, yhlo, mM, lL);

    // att[-1] regeneration from head-7 m,l
    const size_t TD = (size_t)Tn * DH;
    att_kernel<<<dim3(Tn / 128, Tn / 128), blk, 0, stream>>>(
        Qhi + 7 * TD, Qlo + 7 * TD, Khi + 7 * TD, Klo + 7 * TD, mM, lL, out_att);

    // output projection
    gemm_out<<<dim3(Dm / 128, Tn / 128), blk, 0, stream>>>(yhhi, yhlo, Wohi, Wolo, out_y);
}